// Round 9
// baseline (150323.206 us; speedup 1.0000x reference)
//
#include <hip/hip_runtime.h>
#include <math.h>

// Problem sizes (fixed)
#define T_STEPS 32768
#define DIM 512
#define HID 1024
#define SD 256            // state dim S

// 256 persistent WGs (1/CU), 256 threads = 4 waves:
// waves 0,1 = scan (critical path), waves 2,3 = helpers (y-gates + out rows).
#define NWG 256
#define RBT 256

typedef unsigned u32x4 __attribute__((ext_vector_type(4)));

// Pin loaded weights into registers: opaque def prevents per-step re-fetch.
#define PIN4(v) asm volatile("" : "+v"((v).x), "+v"((v).y), "+v"((v).z), "+v"((v).w))

__device__ __forceinline__ float dot4(float4 a, float4 b) {
    return a.x*b.x + a.y*b.y + a.z*b.z + a.w*b.w;
}
__device__ __forceinline__ float sigmoid_fast(float x) {
    float e = __builtin_amdgcn_exp2f(-1.4426950408889634f * x);
    return __builtin_amdgcn_rcpf(1.f + e);
}
__device__ __forceinline__ float tanh_fast(float x) {
    float e = __builtin_amdgcn_exp2f(2.8853900817779268f * x);   // exp(2x)
    return 1.f - 2.f * __builtin_amdgcn_rcpf(e + 1.f);
}
__device__ __forceinline__ float softplus_f(float x) {
    float ax = fabsf(x);
    return fmaxf(x, 0.f) + log1pf(expf(-ax));
}
__device__ __forceinline__ float4 asf4(u32x4 q) {
    return make_float4(__uint_as_float(q.x), __uint_as_float(q.y),
                       __uint_as_float(q.z), __uint_as_float(q.w));
}

// Exact 64-lane sum: 4 DPP stages (xor1,2,7,8) + 2 shfl stages (xor16, xor32).
__device__ __forceinline__ float wave_sum(float v) {
    int x;
    x = __builtin_amdgcn_mov_dpp(__float_as_int(v), 0xB1,  0xf, 0xf, true); v += __int_as_float(x);
    x = __builtin_amdgcn_mov_dpp(__float_as_int(v), 0x4E,  0xf, 0xf, true); v += __int_as_float(x);
    x = __builtin_amdgcn_mov_dpp(__float_as_int(v), 0x141, 0xf, 0xf, true); v += __int_as_float(x);
    x = __builtin_amdgcn_mov_dpp(__float_as_int(v), 0x128, 0xf, 0xf, true); v += __int_as_float(x);
    v += __shfl_xor(v, 16, 64);
    v += __shfl_xor(v, 32, 64);
    return v;
}

// ---------------------------------------------------------------------------
// h state: u32/elem, low 2 bits = step tag (t&3). Buffers by step parity.
// init runs every call (replay-safe; scrubs stale tags).
// ---------------------------------------------------------------------------
__global__ void init_kernel(const float* __restrict__ h0,
                            unsigned* __restrict__ htag) {
    int i = blockIdx.x * 256 + threadIdx.x;      // grid 4 x 256 = 1024
    unsigned v = __float_as_uint(tanhf(h0[i]));
    htag[i]       = v & ~3u;   // h_0, tag 0
    htag[HID + i] = 0u;        // buffer1 scrub (readers expect odd tags)
}

// ---- proven 1-deep spin (rounds 5/7): loads + vmcnt(0) + check in ONE asm
// ---- block; every load retired before exit (round-8 lesson: mandatory). ----
__device__ __forceinline__ void spin1(const unsigned* pa, unsigned tg,
                                      u32x4& q0, u32x4& q1, u32x4& q2, u32x4& q3) {
    for (;;) {
        asm volatile(
            "global_load_dwordx4 %0, %4, off sc0 sc1\n\t"
            "global_load_dwordx4 %1, %4, off offset:16 sc0 sc1\n\t"
            "global_load_dwordx4 %2, %4, off offset:32 sc0 sc1\n\t"
            "global_load_dwordx4 %3, %4, off offset:48 sc0 sc1\n\t"
            "s_waitcnt vmcnt(0)"
            : "=&v"(q0), "=&v"(q1), "=&v"(q2), "=&v"(q3)
            : "v"(pa) : "memory");
        unsigned m = ((q0.x ^ tg) | (q0.y ^ tg)) | ((q0.z ^ tg) | (q0.w ^ tg))
                   | ((q1.x ^ tg) | (q1.y ^ tg)) | ((q1.z ^ tg) | (q1.w ^ tg))
                   | ((q2.x ^ tg) | (q2.y ^ tg)) | ((q2.z ^ tg) | (q2.w ^ tg))
                   | ((q3.x ^ tg) | (q3.y ^ tg)) | ((q3.z ^ tg) | (q3.w ^ tg));
        if ((m & 3u) == 0u) break;
    }
}

// ---------------------------------------------------------------------------
// Wave-specialized persistent scan.
// Scan waves (0,1): spin(htag) -> h-dots -> reduce -> gates (y-gates from LDS,
//   produced 2 steps ahead by helpers) -> publish. Wave 0 then stages its
//   polled h copy into LDS for the helpers (after publish; off critical path).
// Helper waves (2,3): wait staged h -> out row -> produce y-gates for t+2.
// Slot-reuse safety: h tagged t exists => global step t-1 complete => all
// ygate slots <= t-1 consumed (scan reads ygate(t) before publishing t+1).
// hsh[2] reuse guarded by helper progress counter (checked after publish).
// ---------------------------------------------------------------------------
__global__ __launch_bounds__(RBT, 1) void gru_scan(
    const float* __restrict__ y, const float* __restrict__ h0,
    const float* __restrict__ w_ih, const float* __restrict__ w_hh,
    const float* __restrict__ b, const float* __restrict__ bn,
    const float* __restrict__ w_out, const float* __restrict__ b_out,
    float* __restrict__ out, unsigned* __restrict__ htag /* [2][HID] */) {
    const int tid  = threadIdx.x;
    const int wg   = blockIdx.x;
    const int wv   = tid >> 6;          // wave 0..3
    const int lane = tid & 63;
    const int half = lane >> 5;

    __shared__ float hsh[2][HID];       // staged h_t (by scan wave 0)
    __shared__ float ygv[4][2][6];      // [slot t&3][scanwave][uu*3+gate]
    __shared__ int   seqH[2];           // == t+1 when hsh[t&1] holds h_t
    __shared__ int   seqY[8];           // [slot*2+w] == t+1 when ygv ready
    __shared__ int   prog[2];           // helper hw consumed h_{prog-1}
    if (tid < 2) { seqH[tid] = 0; prog[tid] = 0; }
    if (tid < 8) seqY[tid] = 0;
    __syncthreads();
    volatile int* vseqH = seqH;
    volatile int* vseqY = seqY;
    volatile int* vprog = prog;

    const size_t TS = (size_t)T_STEPS * SD;

    if (wv < 2) {
        // ======================= SCAN WAVE =======================
        const int u0 = wg * 4 + wv * 2;
        const int um = u0 + half;       // unit this half-wave finalizes

        float4 wh[3][2][4];             // 96 VGPRs of w_hh, resident
        #pragma unroll
        for (int g = 0; g < 3; ++g)
            #pragma unroll
            for (int uu = 0; uu < 2; ++uu) {
                const float* row = &w_hh[(size_t)(g * HID + u0 + uu) * HID + 16 * lane];
                #pragma unroll
                for (int q = 0; q < 4; ++q) { wh[g][uu][q] = *(const float4*)&row[4*q]; PIN4(wh[g][uu][q]); }
            }
        const float bnu = bn[um];
        float hp = tanhf(h0[um]);

        for (int t = 0; t <= T_STEPS; ++t) {
            const unsigned tg = (unsigned)t & 3u;
            const unsigned* pa = htag + (size_t)((t & 1) * HID + 16 * lane);
            u32x4 q0, q1, q2, q3;
            spin1(pa, tg, q0, q1, q2, q3);
            float4 hv0 = asf4(q0), hv1 = asf4(q1), hv2 = asf4(q2), hv3 = asf4(q3);

            if (t < T_STEPS) {
                // y-gates from LDS (normally ready; ds latency hides in FMAs)
                volatile int* sy = &vseqY[(t & 3) * 2 + wv];
                while (*sy != t + 1) {}
                asm volatile("" ::: "memory");
                const float* yB = ygv[t & 3][wv];
                float yr = yB[half * 3 + 0];
                float yz = yB[half * 3 + 1];
                float yi = yB[half * 3 + 2];

                float s[6];
                #pragma unroll
                for (int g = 0; g < 3; ++g)
                    #pragma unroll
                    for (int uu = 0; uu < 2; ++uu)
                        s[g*2+uu] = dot4(wh[g][uu][0], hv0) + dot4(wh[g][uu][1], hv1)
                                  + dot4(wh[g][uu][2], hv2) + dot4(wh[g][uu][3], hv3);
                #pragma unroll
                for (int k = 0; k < 6; ++k) s[k] = wave_sum(s[k]);

                float r = sigmoid_fast((half ? s[1] : s[0]) + yr);
                float z = sigmoid_fast((half ? s[3] : s[2]) + yz);
                float n = tanh_fast(yi + r * ((half ? s[5] : s[4]) + bnu));
                float hnew = n + z * (hp - n);
                hp = hnew;

                if ((lane & 31) == 0) {
                    unsigned pv = (__float_as_uint(hnew) & ~3u) | (((unsigned)t + 1u) & 3u);
                    unsigned* pp = htag + (size_t)(((t + 1) & 1) * HID + um);
                    asm volatile("global_store_dword %0, %1, off sc0 sc1"
                                 :: "v"(pp), "v"(pv) : "memory");
                }
                __builtin_amdgcn_sched_barrier(0);   // publish before staging
            }

            if (wv == 0) {
                // stage h_t for helpers; WAR-guard: helpers consumed h_{t-2}
                while (vprog[0] < t - 1 || vprog[1] < t - 1) {}
                asm volatile("" ::: "memory");
                float* hd = &hsh[t & 1][16 * lane];
                *(float4*)&hd[0]  = hv0;
                *(float4*)&hd[4]  = hv1;
                *(float4*)&hd[8]  = hv2;
                *(float4*)&hd[12] = hv3;
                asm volatile("s_waitcnt lgkmcnt(0)" ::: "memory");  // data before seq
                if (lane == 0) vseqH[t & 1] = t + 1;
            }
        }
    } else {
        // ======================= HELPER WAVE =======================
        const int hw  = wv - 2;            // serves scan wave hw
        const int us0 = wg * 4 + hw * 2;   // units whose y-gates we produce

        float4 wi[3][2][2];                // 48 VGPRs of w_ih
        #pragma unroll
        for (int g = 0; g < 3; ++g)
            #pragma unroll
            for (int uu = 0; uu < 2; ++uu) {
                const float* row = &w_ih[(size_t)(g * HID + us0 + uu) * DIM + 8 * lane];
                #pragma unroll
                for (int q = 0; q < 2; ++q) { wi[g][uu][q] = *(const float4*)&row[4*q]; PIN4(wi[g][uu][q]); }
            }
        const int c = 2 * wg + hw;         // output column
        float4 wo[4];
        #pragma unroll
        for (int q = 0; q < 4; ++q) {
            wo[q] = *(const float4*)&w_out[(size_t)c * HID + 16 * lane + 4 * q];
            PIN4(wo[q]);
        }
        const float bo = b_out[c];
        float bb[6];
        #pragma unroll
        for (int g = 0; g < 3; ++g)
            #pragma unroll
            for (int uu = 0; uu < 2; ++uu) bb[g*2+uu] = b[g * HID + us0 + uu];

        auto produceY = [&](int tp) {
            float4 ya0 = *(const float4*)&y[(size_t)tp * DIM + 8 * lane];
            float4 ya1 = *(const float4*)&y[(size_t)tp * DIM + 8 * lane + 4];
            float d[6];
            #pragma unroll
            for (int g = 0; g < 3; ++g)
                #pragma unroll
                for (int uu = 0; uu < 2; ++uu)
                    d[g*2+uu] = dot4(wi[g][uu][0], ya0) + dot4(wi[g][uu][1], ya1);
            #pragma unroll
            for (int k = 0; k < 6; ++k) d[k] = wave_sum(d[k]) + bb[k];
            if (lane == 0) {
                float* e = ygv[tp & 3][hw];
                e[0] = d[0]; e[1] = d[2]; e[2] = d[4];   // unit 0: r,z,i
                e[3] = d[1]; e[4] = d[3]; e[5] = d[5];   // unit 1: r,z,i
            }
            asm volatile("s_waitcnt lgkmcnt(0)" ::: "memory");  // data before seq
            if (lane == 0) vseqY[(tp & 3) * 2 + hw] = tp + 1;
        };

        produceY(0);
        produceY(1);

        for (int t = 0; t <= T_STEPS; ++t) {
            volatile int* sh = &vseqH[t & 1];
            while (*sh != t + 1) {}
            asm volatile("" ::: "memory");
            const float* hd = &hsh[t & 1][16 * lane];
            float4 a0 = *(const float4*)&hd[0];
            float4 a1 = *(const float4*)&hd[4];
            float4 a2 = *(const float4*)&hd[8];
            float4 a3 = *(const float4*)&hd[12];
            asm volatile("s_waitcnt lgkmcnt(0)" ::: "memory");  // in regs now
            if (lane == 0) vprog[hw] = t + 1;                   // release slot

            if (t > 0) {                                        // out row t-1
                float p = dot4(wo[0], a0) + dot4(wo[1], a1)
                        + dot4(wo[2], a2) + dot4(wo[3], a3);
                p = wave_sum(p);
                if (lane == 0) {
                    float v = p + bo;
                    size_t row = (size_t)(t - 1);
                    if (c >= SD) out[TS + row * SD + (c - SD)] = softplus_f(v);
                    else         out[row * SD + c] = v;
                }
            }
            if (t + 2 < T_STEPS) produceY(t + 2);
        }
    }
    asm volatile("s_waitcnt vmcnt(0)" ::: "memory");   // drain stores
}

// ---------------------------------------------------------------------------
extern "C" void kernel_launch(void* const* d_in, const int* in_sizes, int n_in,
                              void* d_out, int out_size, void* d_ws, size_t ws_size,
                              hipStream_t stream) {
    const float* y     = (const float*)d_in[0];
    const float* h0    = (const float*)d_in[1];
    const float* w_ih  = (const float*)d_in[2];
    const float* w_hh  = (const float*)d_in[3];
    const float* b     = (const float*)d_in[4];
    const float* bn    = (const float*)d_in[5];
    const float* w_out = (const float*)d_in[6];
    const float* b_out = (const float*)d_in[7];
    float* out = (float*)d_out;

    unsigned* htag = (unsigned*)d_ws;   // [2][HID] u32 = 8 KB

    hipLaunchKernelGGL(init_kernel, dim3(4), dim3(256), 0, stream, h0, htag);
    hipLaunchKernelGGL(gru_scan, dim3(NWG), dim3(RBT), 0, stream,
                       y, h0, w_ih, w_hh, b, bn, w_out, b_out, out, htag);
}

// Round 10
// 60928.149 us; speedup vs baseline: 2.4672x; 2.4672x over previous
//
#include <hip/hip_runtime.h>
#include <math.h>

// Problem sizes (fixed)
#define T_STEPS 32768
#define DIM 512
#define HID 1024
#define SD 256            // state dim S

// 256 persistent WGs (1/CU), 128 threads = 2 independent waves, 2 units/wave.
#define NWG 256
#define RBT 128

typedef unsigned u32x4 __attribute__((ext_vector_type(4)));

// Pin loaded weights into registers: opaque def prevents per-step re-fetch.
#define PIN4(v) asm volatile("" : "+v"((v).x), "+v"((v).y), "+v"((v).z), "+v"((v).w))

__device__ __forceinline__ float dot4(float4 a, float4 b) {
    return a.x*b.x + a.y*b.y + a.z*b.z + a.w*b.w;
}
__device__ __forceinline__ float sigmoid_fast(float x) {
    float e = __builtin_amdgcn_exp2f(-1.4426950408889634f * x);
    return __builtin_amdgcn_rcpf(1.f + e);
}
__device__ __forceinline__ float tanh_fast(float x) {
    float e = __builtin_amdgcn_exp2f(2.8853900817779268f * x);   // exp(2x)
    return 1.f - 2.f * __builtin_amdgcn_rcpf(e + 1.f);
}
__device__ __forceinline__ float softplus_f(float x) {
    float ax = fabsf(x);
    return fmaxf(x, 0.f) + log1pf(expf(-ax));
}
// round-to-nearest-even fp32 -> bf16 (16-bit result in low half)
__device__ __forceinline__ unsigned bf16rne(float x) {
    unsigned b = __float_as_uint(x);
    return (b + 0x7FFFu + ((b >> 16) & 1u)) >> 16;
}

// Exact 64-lane sum: 4 DPP stages (xor1,2,7,8) + 2 shfl stages (xor16, xor32).
__device__ __forceinline__ float wave_sum(float v) {
    int x;
    x = __builtin_amdgcn_mov_dpp(__float_as_int(v), 0xB1,  0xf, 0xf, true); v += __int_as_float(x);
    x = __builtin_amdgcn_mov_dpp(__float_as_int(v), 0x4E,  0xf, 0xf, true); v += __int_as_float(x);
    x = __builtin_amdgcn_mov_dpp(__float_as_int(v), 0x141, 0xf, 0xf, true); v += __int_as_float(x);
    x = __builtin_amdgcn_mov_dpp(__float_as_int(v), 0x128, 0xf, 0xf, true); v += __int_as_float(x);
    v += __shfl_xor(v, 16, 64);
    v += __shfl_xor(v, 32, 64);
    return v;
}

// ---------------------------------------------------------------------------
// h state: hb16[2][512] dwords. dword k of buffer b = {lo: bf16(h[2k]),
// hi: bf16(h[2k+1])}, each bf16's mantissa LSB = tag bit ((t>>1)&1).
// Staleness proof (round-5 structure): a reader at step t reaching the poll
// implies global step t-1 done implies buffer (t&1) was overwritten at step
// t-2's publish at the latest -> observable content is step t or t-2 only;
// their tag bits differ (t, t-2 differ in bit 1). Buffer1 scrub = 0x00010001
// (tag 1): readers at t=1 expect tag 0, and by t=3 (first tag-1 reader) the
// scrub is provably overwritten. One dword per unit-pair -> pair is atomic.
// ---------------------------------------------------------------------------
__global__ void init_kernel(const float* __restrict__ h0,
                            unsigned* __restrict__ hb16) {
    int i = blockIdx.x * 256 + threadIdx.x;      // grid 4 x 256 = 1024
    if (i < 512) {
        unsigned lo = bf16rne(tanhf(h0[2 * i]))     & 0xFFFEu;
        unsigned hi = bf16rne(tanhf(h0[2 * i + 1])) & 0xFFFEu;
        hb16[i] = lo | (hi << 16);                // h_0, tag bit 0
    } else {
        hb16[i] = 0x00010001u;                    // buffer1 scrub (tag 1)
    }
}

#define TAGM(m, pat)                                                           \
    m = ((q0.x ^ pat) | (q0.y ^ pat)) | ((q0.z ^ pat) | (q0.w ^ pat))          \
      | ((q1.x ^ pat) | (q1.y ^ pat)) | ((q1.z ^ pat) | (q1.w ^ pat))

#define UNPK(w, lo, hi)                                                        \
    lo = __uint_as_float((w << 16) & 0xFFFE0000u);                             \
    hi = __uint_as_float(w & 0xFFFE0000u);

// ---------------------------------------------------------------------------
// persistent fused scan, wave-granular (no LDS, no barriers). Protocol
// skeleton identical to round 7 (proven); payload is now bf16-packed:
// poll = 2x dwordx4 (32B/lane, halves MALL read traffic), publish = ONE
// dword per wave (pair combined via shfl_xor 32; halves store count).
// Every asm block retires all its loads internally (round-8 rule).
// ---------------------------------------------------------------------------
__global__ __launch_bounds__(RBT, 1) void gru_scan(
    const float* __restrict__ y, const float* __restrict__ h0,
    const float* __restrict__ w_ih, const float* __restrict__ w_hh,
    const float* __restrict__ b, const float* __restrict__ bn,
    const float* __restrict__ w_out, const float* __restrict__ b_out,
    float* __restrict__ out, unsigned* __restrict__ hb16 /* [2][512] */) {
    const int tid  = threadIdx.x;
    const int wg   = blockIdx.x;
    const int wv   = tid >> 6;          // wave 0..1
    const int lane = tid & 63;
    const int half = lane >> 5;         // 0: unit u0, 1: unit u0+1
    const int u0   = wg * 4 + wv * 2;
    const int um   = u0 + half;         // unit this half-wave finalizes

    // hidden weights wh[gate][unit][q]: 16 elems/lane at 16*lane
    float4 wh[3][2][4];
    #pragma unroll
    for (int g = 0; g < 3; ++g)
        #pragma unroll
        for (int uu = 0; uu < 2; ++uu) {
            const float* row = &w_hh[(size_t)(g * HID + u0 + uu) * HID + 16 * lane];
            #pragma unroll
            for (int q = 0; q < 4; ++q) { wh[g][uu][q] = *(const float4*)&row[4*q]; PIN4(wh[g][uu][q]); }
        }
    // input weights wi[gate][unit][q]: 8 elems/lane at 8*lane
    float4 wi[3][2][2];
    #pragma unroll
    for (int g = 0; g < 3; ++g)
        #pragma unroll
        for (int uu = 0; uu < 2; ++uu) {
            const float* row = &w_ih[(size_t)(g * HID + u0 + uu) * DIM + 8 * lane];
            #pragma unroll
            for (int q = 0; q < 2; ++q) { wi[g][uu][q] = *(const float4*)&row[4*q]; PIN4(wi[g][uu][q]); }
        }
    // output weights: col c = 2*wg + wv, 16 elems/lane
    const int c = 2 * wg + wv;
    float4 wo[4];
    #pragma unroll
    for (int q = 0; q < 4; ++q) {
        wo[q] = *(const float4*)&w_out[(size_t)c * HID + 16 * lane + 4 * q];
        PIN4(wo[q]);
    }

    const float bi_r = b[um], bi_z = b[HID + um], bi_n = b[2 * HID + um];
    const float bnu  = bn[um];
    const float bo   = b_out[c];

    float hp = tanhf(h0[um]);           // own unit's h, fp32 in-register

    // y-side pre-reduced gate inputs (+bias) for step t (t=0 in prologue)
    float yr, yz, yi;
    {
        float4 ya0 = *(const float4*)&y[8 * lane];
        float4 ya1 = *(const float4*)&y[8 * lane + 4];
        float d[6];
        #pragma unroll
        for (int g = 0; g < 3; ++g)
            #pragma unroll
            for (int uu = 0; uu < 2; ++uu)
                d[g*2+uu] = dot4(wi[g][uu][0], ya0) + dot4(wi[g][uu][1], ya1);
        #pragma unroll
        for (int k = 0; k < 6; ++k) d[k] = wave_sum(d[k]);
        yr = (half ? d[1] : d[0]) + bi_r;
        yz = (half ? d[3] : d[2]) + bi_z;
        yi = (half ? d[5] : d[4]) + bi_n;
    }

    const size_t TS = (size_t)T_STEPS * SD;

    for (int t = 0; t <= T_STEPS; ++t) {
        const unsigned pat = (((unsigned)t >> 1) & 1u) * 0x00010001u;
        const unsigned* pa = hb16 + (size_t)((t & 1) * 512 + 8 * lane);
        const int tn = (t + 1 < T_STEPS) ? (t + 1) : 0;       // OOB clamp
        const float* ya = &y[(size_t)tn * DIM + 8 * lane];

        // ---- poll (fused y prefetch); all loads retired by internal vmcnt(0)
        u32x4 q0, q1, yq0, yq1;
        asm volatile(
            "global_load_dwordx4 %[y0], %[ya], off\n\t"
            "global_load_dwordx4 %[y1], %[ya], off offset:16\n\t"
            "global_load_dwordx4 %[q0], %[pa], off sc0 sc1\n\t"
            "global_load_dwordx4 %[q1], %[pa], off offset:16 sc0 sc1\n\t"
            "s_waitcnt vmcnt(0)"
            : [q0]"=&v"(q0), [q1]"=&v"(q1), [y0]"=&v"(yq0), [y1]"=&v"(yq1)
            : [pa]"v"(pa), [ya]"v"(ya)
            : "memory");
        unsigned m; TAGM(m, pat);
        while ((m & 0x00010001u) != 0u) {
            asm volatile(
                "global_load_dwordx4 %[q0], %[pa], off sc0 sc1\n\t"
                "global_load_dwordx4 %[q1], %[pa], off offset:16 sc0 sc1\n\t"
                "s_waitcnt vmcnt(0)"
                : [q0]"=&v"(q0), [q1]"=&v"(q1)
                : [pa]"v"(pa)
                : "memory");
            TAGM(m, pat);
        }
        // unpack 8 dwords -> 16 fp32 h values (units 16*lane .. 16*lane+15)
        float4 hv0, hv1, hv2, hv3;
        UNPK(q0.x, hv0.x, hv0.y) UNPK(q0.y, hv0.z, hv0.w)
        UNPK(q0.z, hv1.x, hv1.y) UNPK(q0.w, hv1.z, hv1.w)
        UNPK(q1.x, hv2.x, hv2.y) UNPK(q1.y, hv2.z, hv2.w)
        UNPK(q1.z, hv3.x, hv3.y) UNPK(q1.w, hv3.z, hv3.w)

        // ---- critical path: 96 FMA -> 6-val reduce -> gates -> publish ----
        if (t < T_STEPS) {
            float s[6];
            #pragma unroll
            for (int g = 0; g < 3; ++g)
                #pragma unroll
                for (int uu = 0; uu < 2; ++uu)
                    s[g*2+uu] = dot4(wh[g][uu][0], hv0) + dot4(wh[g][uu][1], hv1)
                              + dot4(wh[g][uu][2], hv2) + dot4(wh[g][uu][3], hv3);
            #pragma unroll
            for (int k = 0; k < 6; ++k) s[k] = wave_sum(s[k]);

            float r = sigmoid_fast((half ? s[1] : s[0]) + yr);
            float z = sigmoid_fast((half ? s[3] : s[2]) + yz);
            float n = tanh_fast(yi + r * ((half ? s[5] : s[4]) + bnu));
            float hnew = n + z * (hp - n);
            hp = hnew;

            // pack the wave's unit pair into one dword and publish (lane 0)
            unsigned u16 = bf16rne(hnew) & 0xFFFEu;
            unsigned other = __shfl_xor(u16, 32, 64);   // lane0 <- lane32
            if (lane == 0) {
                unsigned tb1 = (((unsigned)t + 1u) >> 1) & 1u;
                unsigned pv = (u16 | tb1) | ((other | tb1) << 16);
                unsigned* pp = hb16 + (size_t)(((t + 1) & 1) * 512 + (2 * wg + wv));
                asm volatile("global_store_dword %0, %1, off sc0 sc1"
                             :: "v"(pp), "v"(pv) : "memory");
            }
            __builtin_amdgcn_sched_barrier(0);   // publish before any tail work
        }

        // ---- tail (registers only; NO vmem-dependent uses -> no waitcnt) ----
        {
            float4 ya0 = make_float4(__uint_as_float(yq0.x), __uint_as_float(yq0.y),
                                     __uint_as_float(yq0.z), __uint_as_float(yq0.w));
            float4 ya1 = make_float4(__uint_as_float(yq1.x), __uint_as_float(yq1.y),
                                     __uint_as_float(yq1.z), __uint_as_float(yq1.w));
            float d[6];
            #pragma unroll
            for (int g = 0; g < 3; ++g)
                #pragma unroll
                for (int uu = 0; uu < 2; ++uu)
                    d[g*2+uu] = dot4(wi[g][uu][0], ya0) + dot4(wi[g][uu][1], ya1);
            #pragma unroll
            for (int k = 0; k < 6; ++k) d[k] = wave_sum(d[k]);
            yr = (half ? d[1] : d[0]) + bi_r;
            yz = (half ? d[3] : d[2]) + bi_z;
            yi = (half ? d[5] : d[4]) + bi_n;
        }

        // out row t-1 from this iteration's polled h (hs[t-1] = h_t), in regs
        if (t > 0) {
            float p = dot4(wo[0], hv0) + dot4(wo[1], hv1)
                    + dot4(wo[2], hv2) + dot4(wo[3], hv3);
            p = wave_sum(p);
            if (lane == 0) {
                float v = p + bo;
                size_t row = (size_t)(t - 1);
                if (c >= SD) out[TS + row * SD + (c - SD)] = softplus_f(v);
                else         out[row * SD + c] = v;       // fire-and-forget
            }
        }
    }
    asm volatile("s_waitcnt vmcnt(0)" ::: "memory");   // drain stores
}

// ---------------------------------------------------------------------------
extern "C" void kernel_launch(void* const* d_in, const int* in_sizes, int n_in,
                              void* d_out, int out_size, void* d_ws, size_t ws_size,
                              hipStream_t stream) {
    const float* y     = (const float*)d_in[0];
    const float* h0    = (const float*)d_in[1];
    const float* w_ih  = (const float*)d_in[2];
    const float* w_hh  = (const float*)d_in[3];
    const float* b     = (const float*)d_in[4];
    const float* bn    = (const float*)d_in[5];
    const float* w_out = (const float*)d_in[6];
    const float* b_out = (const float*)d_in[7];
    float* out = (float*)d_out;

    unsigned* hb16 = (unsigned*)d_ws;   // [2][512] u32 = 4 KB

    hipLaunchKernelGGL(init_kernel, dim3(4), dim3(256), 0, stream, h0, hb16);
    hipLaunchKernelGGL(gru_scan, dim3(NWG), dim3(RBT), 0, stream,
                       y, h0, w_ih, w_hh, b, bn, w_out, b_out, out, hb16);
}

// Round 11
// 47910.986 us; speedup vs baseline: 3.1376x; 1.2717x over previous
//
#include <hip/hip_runtime.h>
#include <math.h>

// Problem sizes (fixed)
#define T_STEPS 32768
#define DIM 512
#define HID 1024
#define SD 256            // state dim S

// 256 persistent WGs (1/CU), 128 threads = 2 independent waves, 2 units/wave.
#define NWG 256
#define RBT 128

typedef unsigned u32x4 __attribute__((ext_vector_type(4)));
typedef float    f32x2 __attribute__((ext_vector_type(2)));

// Pin loaded weights into registers: opaque def prevents per-step re-fetch.
#define PIN2(v) asm volatile("" : "+v"((v).x), "+v"((v).y))

__device__ __forceinline__ float sigmoid_fast(float x) {
    float e = __builtin_amdgcn_exp2f(-1.4426950408889634f * x);
    return __builtin_amdgcn_rcpf(1.f + e);
}
__device__ __forceinline__ float tanh_fast(float x) {
    float e = __builtin_amdgcn_exp2f(2.8853900817779268f * x);   // exp(2x)
    return 1.f - 2.f * __builtin_amdgcn_rcpf(e + 1.f);
}
__device__ __forceinline__ float softplus_f(float x) {
    float ax = fabsf(x);
    return fmaxf(x, 0.f) + log1pf(expf(-ax));
}

// Exact 64-lane sum: 4 DPP stages (xor1,2,7,8) + 2 shfl stages (xor16, xor32).
__device__ __forceinline__ float wave_sum(float v) {
    int x;
    x = __builtin_amdgcn_mov_dpp(__float_as_int(v), 0xB1,  0xf, 0xf, true); v += __int_as_float(x);
    x = __builtin_amdgcn_mov_dpp(__float_as_int(v), 0x4E,  0xf, 0xf, true); v += __int_as_float(x);
    x = __builtin_amdgcn_mov_dpp(__float_as_int(v), 0x141, 0xf, 0xf, true); v += __int_as_float(x);
    x = __builtin_amdgcn_mov_dpp(__float_as_int(v), 0x128, 0xf, 0xf, true); v += __int_as_float(x);
    v += __shfl_xor(v, 16, 64);
    v += __shfl_xor(v, 32, 64);
    return v;
}

// ---------------------------------------------------------------------------
// h state: u32/elem, low 2 bits = step tag (t&3). Buffers by step parity.
// init runs every call (replay-safe; scrubs stale tags).
// ---------------------------------------------------------------------------
__global__ void init_kernel(const float* __restrict__ h0,
                            unsigned* __restrict__ htag) {
    int i = blockIdx.x * 256 + threadIdx.x;      // grid 4 x 256 = 1024
    unsigned v = __float_as_uint(tanhf(h0[i]));
    htag[i]       = v & ~3u;   // h_0, tag 0
    htag[HID + i] = 0u;        // buffer1 scrub (readers expect odd tags)
}

#define TAGCHK(m, tg)                                                          \
    m = ((q0.x ^ tg) | (q0.y ^ tg)) | ((q0.z ^ tg) | (q0.w ^ tg))              \
      | ((q1.x ^ tg) | (q1.y ^ tg)) | ((q1.z ^ tg) | (q1.w ^ tg))              \
      | ((q2.x ^ tg) | (q2.y ^ tg)) | ((q2.z ^ tg) | (q2.w ^ tg))              \
      | ((q3.x ^ tg) | (q3.y ^ tg)) | ((q3.z ^ tg) | (q3.w ^ tg))

// ---------------------------------------------------------------------------
// persistent fused scan, wave-granular (no LDS, no barriers). Protocol
// byte-equivalent to round 7 (proven, 50.3 ms/dispatch): 1-deep spin with
// fused y-prefetch, all loads retired inside each asm block, register-only
// tail (no vmem-dependent uses -> no compiler vmcnt drain of the publish).
// Only change: dot products in f32x2 vector arithmetic so the backend can
// form v_pk_fma_f32 (halves FMA issue on the detect->publish serial path).
// ---------------------------------------------------------------------------
__global__ __launch_bounds__(RBT, 1) void gru_scan(
    const float* __restrict__ y, const float* __restrict__ h0,
    const float* __restrict__ w_ih, const float* __restrict__ w_hh,
    const float* __restrict__ b, const float* __restrict__ bn,
    const float* __restrict__ w_out, const float* __restrict__ b_out,
    float* __restrict__ out, unsigned* __restrict__ htag /* [2][HID] */) {
    const int tid  = threadIdx.x;
    const int wg   = blockIdx.x;
    const int wv   = tid >> 6;          // wave 0..1
    const int lane = tid & 63;
    const int half = lane >> 5;         // 0: unit u0, 1: unit u0+1
    const int u0   = wg * 4 + wv * 2;
    const int um   = u0 + half;         // unit this half-wave finalizes

    // hidden weights: 16 elems/lane at 16*lane, as 8 f32x2 per (gate,unit)
    f32x2 wh[3][2][8];
    #pragma unroll
    for (int g = 0; g < 3; ++g)
        #pragma unroll
        for (int uu = 0; uu < 2; ++uu) {
            const f32x2* row = (const f32x2*)&w_hh[(size_t)(g * HID + u0 + uu) * HID + 16 * lane];
            #pragma unroll
            for (int q = 0; q < 8; ++q) { wh[g][uu][q] = row[q]; PIN2(wh[g][uu][q]); }
        }
    // input weights: 8 elems/lane at 8*lane, as 4 f32x2 per (gate,unit)
    f32x2 wi[3][2][4];
    #pragma unroll
    for (int g = 0; g < 3; ++g)
        #pragma unroll
        for (int uu = 0; uu < 2; ++uu) {
            const f32x2* row = (const f32x2*)&w_ih[(size_t)(g * HID + u0 + uu) * DIM + 8 * lane];
            #pragma unroll
            for (int q = 0; q < 4; ++q) { wi[g][uu][q] = row[q]; PIN2(wi[g][uu][q]); }
        }
    // output weights: col c = 2*wg + wv, 16 elems/lane as 8 f32x2
    const int c = 2 * wg + wv;
    f32x2 wo[8];
    #pragma unroll
    for (int q = 0; q < 8; ++q) {
        wo[q] = ((const f32x2*)&w_out[(size_t)c * HID + 16 * lane])[q];
        PIN2(wo[q]);
    }

    const float bi_r = b[um], bi_z = b[HID + um], bi_n = b[2 * HID + um];
    const float bnu  = bn[um];
    const float bo   = b_out[c];

    float hp = tanhf(h0[um]);           // own unit's h, fp32 in-register

    // y-side pre-reduced gate inputs (+bias) for step t (t=0 in prologue)
    float yr, yz, yi;
    {
        const f32x2* yv = (const f32x2*)&y[8 * lane];
        f32x2 acc[6] = {};
        #pragma unroll
        for (int g = 0; g < 3; ++g)
            #pragma unroll
            for (int uu = 0; uu < 2; ++uu)
                #pragma unroll
                for (int q = 0; q < 4; ++q)
                    acc[g*2+uu] = wi[g][uu][q] * yv[q] + acc[g*2+uu];
        float d[6];
        #pragma unroll
        for (int k = 0; k < 6; ++k) d[k] = wave_sum(acc[k].x + acc[k].y);
        yr = (half ? d[1] : d[0]) + bi_r;
        yz = (half ? d[3] : d[2]) + bi_z;
        yi = (half ? d[5] : d[4]) + bi_n;
    }

    const size_t TS = (size_t)T_STEPS * SD;

    for (int t = 0; t <= T_STEPS; ++t) {
        const unsigned tg = (unsigned)t & 3u;
        const unsigned* pa = htag + (size_t)((t & 1) * HID + 16 * lane);
        const int tn = (t + 1 < T_STEPS) ? (t + 1) : 0;       // OOB clamp
        const float* ya = &y[(size_t)tn * DIM + 8 * lane];

        // ---- 1-deep spin, fused y(t+1) prefetch; every load retired by the
        // ---- internal vmcnt(0) (nothing in flight crosses the asm boundary)
        u32x4 q0, q1, q2, q3, yq0, yq1;
        asm volatile(
            "global_load_dwordx4 %[y0], %[ya], off\n\t"
            "global_load_dwordx4 %[y1], %[ya], off offset:16\n\t"
            "global_load_dwordx4 %[q0], %[pa], off sc0 sc1\n\t"
            "global_load_dwordx4 %[q1], %[pa], off offset:16 sc0 sc1\n\t"
            "global_load_dwordx4 %[q2], %[pa], off offset:32 sc0 sc1\n\t"
            "global_load_dwordx4 %[q3], %[pa], off offset:48 sc0 sc1\n\t"
            "s_waitcnt vmcnt(0)"
            : [q0]"=&v"(q0), [q1]"=&v"(q1), [q2]"=&v"(q2), [q3]"=&v"(q3),
              [y0]"=&v"(yq0), [y1]"=&v"(yq1)
            : [pa]"v"(pa), [ya]"v"(ya)
            : "memory");
        unsigned m; TAGCHK(m, tg);
        while ((m & 3u) != 0u) {
            asm volatile(
                "global_load_dwordx4 %[q0], %[pa], off sc0 sc1\n\t"
                "global_load_dwordx4 %[q1], %[pa], off offset:16 sc0 sc1\n\t"
                "global_load_dwordx4 %[q2], %[pa], off offset:32 sc0 sc1\n\t"
                "global_load_dwordx4 %[q3], %[pa], off offset:48 sc0 sc1\n\t"
                "s_waitcnt vmcnt(0)"
                : [q0]"=&v"(q0), [q1]"=&v"(q1), [q2]"=&v"(q2), [q3]"=&v"(q3)
                : [pa]"v"(pa)
                : "memory");
            TAGCHK(m, tg);
        }
        // h values as 8 f32x2 (tag bits in mantissa LSBs: error 2^-21, benign)
        f32x2 hv[8];
        hv[0] = f32x2{__uint_as_float(q0.x), __uint_as_float(q0.y)};
        hv[1] = f32x2{__uint_as_float(q0.z), __uint_as_float(q0.w)};
        hv[2] = f32x2{__uint_as_float(q1.x), __uint_as_float(q1.y)};
        hv[3] = f32x2{__uint_as_float(q1.z), __uint_as_float(q1.w)};
        hv[4] = f32x2{__uint_as_float(q2.x), __uint_as_float(q2.y)};
        hv[5] = f32x2{__uint_as_float(q2.z), __uint_as_float(q2.w)};
        hv[6] = f32x2{__uint_as_float(q3.x), __uint_as_float(q3.y)};
        hv[7] = f32x2{__uint_as_float(q3.z), __uint_as_float(q3.w)};

        // ---- critical path: 48 pk-FMA -> 6 reduces -> gates -> publish ----
        if (t < T_STEPS) {
            f32x2 acc[6] = {};
            #pragma unroll
            for (int g = 0; g < 3; ++g)
                #pragma unroll
                for (int uu = 0; uu < 2; ++uu)
                    #pragma unroll
                    for (int q = 0; q < 8; ++q)
                        acc[g*2+uu] = wh[g][uu][q] * hv[q] + acc[g*2+uu];
            // issue order: r (0,1) and n (4,5) chains first (feed tanh), z last
            float s[6];
            s[0] = wave_sum(acc[0].x + acc[0].y);
            s[1] = wave_sum(acc[1].x + acc[1].y);
            s[4] = wave_sum(acc[4].x + acc[4].y);
            s[5] = wave_sum(acc[5].x + acc[5].y);
            s[2] = wave_sum(acc[2].x + acc[2].y);
            s[3] = wave_sum(acc[3].x + acc[3].y);

            float r = sigmoid_fast((half ? s[1] : s[0]) + yr);
            float z = sigmoid_fast((half ? s[3] : s[2]) + yz);
            float n = tanh_fast(yi + r * ((half ? s[5] : s[4]) + bnu));
            float hnew = n + z * (hp - n);
            hp = hnew;

            if ((lane & 31) == 0) {
                unsigned pv = (__float_as_uint(hnew) & ~3u) | (((unsigned)t + 1u) & 3u);
                unsigned* pp = htag + (size_t)(((t + 1) & 1) * HID + um);
                asm volatile("global_store_dword %0, %1, off sc0 sc1"
                             :: "v"(pp), "v"(pv) : "memory");
            }
            __builtin_amdgcn_sched_barrier(0);   // publish before any tail work
        }

        // ---- tail (registers only; NO vmem-dependent uses -> no waitcnt) ----
        {
            f32x2 yv[4];
            yv[0] = f32x2{__uint_as_float(yq0.x), __uint_as_float(yq0.y)};
            yv[1] = f32x2{__uint_as_float(yq0.z), __uint_as_float(yq0.w)};
            yv[2] = f32x2{__uint_as_float(yq1.x), __uint_as_float(yq1.y)};
            yv[3] = f32x2{__uint_as_float(yq1.z), __uint_as_float(yq1.w)};
            f32x2 acc[6] = {};
            #pragma unroll
            for (int g = 0; g < 3; ++g)
                #pragma unroll
                for (int uu = 0; uu < 2; ++uu)
                    #pragma unroll
                    for (int q = 0; q < 4; ++q)
                        acc[g*2+uu] = wi[g][uu][q] * yv[q] + acc[g*2+uu];
            float d[6];
            #pragma unroll
            for (int k = 0; k < 6; ++k) d[k] = wave_sum(acc[k].x + acc[k].y);
            yr = (half ? d[1] : d[0]) + bi_r;
            yz = (half ? d[3] : d[2]) + bi_z;
            yi = (half ? d[5] : d[4]) + bi_n;
        }

        // out row t-1 from this iteration's polled h (hs[t-1] = h_t), in regs
        if (t > 0) {
            f32x2 acc = {};
            #pragma unroll
            for (int q = 0; q < 8; ++q) acc = wo[q] * hv[q] + acc;
            float p = wave_sum(acc.x + acc.y);
            if (lane == 0) {
                float v = p + bo;
                size_t row = (size_t)(t - 1);
                if (c >= SD) out[TS + row * SD + (c - SD)] = softplus_f(v);
                else         out[row * SD + c] = v;       // fire-and-forget
            }
        }
    }
    asm volatile("s_waitcnt vmcnt(0)" ::: "memory");   // drain stores
}

// ---------------------------------------------------------------------------
extern "C" void kernel_launch(void* const* d_in, const int* in_sizes, int n_in,
                              void* d_out, int out_size, void* d_ws, size_t ws_size,
                              hipStream_t stream) {
    const float* y     = (const float*)d_in[0];
    const float* h0    = (const float*)d_in[1];
    const float* w_ih  = (const float*)d_in[2];
    const float* w_hh  = (const float*)d_in[3];
    const float* b     = (const float*)d_in[4];
    const float* bn    = (const float*)d_in[5];
    const float* w_out = (const float*)d_in[6];
    const float* b_out = (const float*)d_in[7];
    float* out = (float*)d_out;

    unsigned* htag = (unsigned*)d_ws;   // [2][HID] u32 = 8 KB

    hipLaunchKernelGGL(init_kernel, dim3(4), dim3(256), 0, stream, h0, htag);
    hipLaunchKernelGGL(gru_scan, dim3(NWG), dim3(RBT), 0, stream,
                       y, h0, w_ih, w_hh, b, bn, w_out, b_out, out, htag);
}